// Round 9
// baseline (315.869 us; speedup 1.0000x reference)
//
#include <hip/hip_runtime.h>
#include <stdint.h>

typedef unsigned short u16;
typedef __attribute__((ext_vector_type(8))) short short8;
typedef __attribute__((ext_vector_type(4))) float f32x4;

#define KGU  5120
#define NPD  2560
#define KD   27648
#define SPLITD 12
#define KCHD 2304            // 27648/12
#define PEL (256*2560)

__device__ __forceinline__ uint32_t f2bf(float x) {
  uint32_t b = __float_as_uint(x);
  return (b + 0x7fffu + ((b >> 16) & 1u)) >> 16;
}
__device__ __forceinline__ uint32_t pk2(float lo, float hi) { return f2bf(lo) | (f2bf(hi) << 16); }
__device__ __forceinline__ uint32_t cvtpk(float lo, float hi) {
  uint32_t r;
  asm("v_cvt_pk_bf16_f32 %0, %1, %2" : "=v"(r) : "v"(lo), "v"(hi));
  return r;
}
__device__ __forceinline__ float silu(float x) {
  return x * __builtin_amdgcn_rcpf(1.f + __expf(-x));
}
#define MFMA16(a,b,c) __builtin_amdgcn_mfma_f32_16x16x32_bf16(a, b, c, 0, 0, 0)

// ---------------- kernel 0: x fp32 -> XF bf16, MFMA-fragment order ----------------
__global__ __launch_bounds__(256) void k_cvt(const float* __restrict__ X, u16* __restrict__ XF) {
  const int kt = blockIdx.x;
  const int lane = threadIdx.x & 63, wv = threadIdx.x >> 6;
#pragma unroll
  for (int ii = 0; ii < 4; ++ii) {
    const int mt = wv * 4 + ii;
    const float* src = X + (size_t)(mt * 16 + (lane & 15)) * KGU + kt * 32 + (lane >> 4) * 8;
    float4 f0 = *(const float4*)src;
    float4 f1 = *(const float4*)(src + 4);
    uint4 v;
    v.x = cvtpk(f0.x, f0.y); v.y = cvtpk(f0.z, f0.w);
    v.z = cvtpk(f1.x, f1.y); v.w = cvtpk(f1.z, f1.w);
    *(uint4*)(XF + ((size_t)(kt * 16 + mt) * 64 + lane) * 8) = v;
  }
}

// ---------------- kernel 1: gate+up GEMM, BM=256 x 64 cols (32 pairs), SK=128 ----------------
// 1024 thr / 16 waves (16M x 1N): wave = 16 rows x 64 cols, 16 MFMA per period.
// Grid 432 XCD-chunked -> 27 waves/CU occupancy cap. A: loop-carried reg frags from XF (L2,
// 1KB-contiguous, 1x redundancy). B: dist-2 reg sets -> cvt once -> swizzled LDS dbuf.
// One s_barrier + lgkmcnt(0) per SK=128 period (40 periods); no vmcnt(0) in loop.
__global__ __launch_bounds__(1024, 6)
void k_gu(const u16* __restrict__ XF,
          const float* __restrict__ Wg, const float* __restrict__ bg,
          const float* __restrict__ W1g, const float* __restrict__ b1g,
          const float* __restrict__ W2g, const float* __restrict__ b2g,
          const float* __restrict__ Wu, const float* __restrict__ bu,
          const float* __restrict__ W1u, const float* __restrict__ b1u,
          const float* __restrict__ W2u, const float* __restrict__ b2u,
          u16* __restrict__ HF) {
  __shared__ __align__(16) char smem[32768 + 1536];   // 2 x 16KB B tiles + consts
  const int tid = threadIdx.x, lane = tid & 63, wid = tid >> 6;   // wid 0..15
  const int s_ = lane & 15, quad = lane >> 4;
  const int bx = blockIdx.x;
  const int w = (bx & 7) * 54 + (bx >> 3);
  const int j0p = w * 32;

  float4* mc4 = (float4*)(smem + 32768);
  float*  mc1 = (float*)(smem + 32768 + 1024);
  if (tid < 64) {
    int sel = tid >> 5, m = tid & 31;
    const float* w1 = (sel ? W1u : W1g) + m * 6;
    const float* b1 = sel ? b1u : b1g;
    const float* w2 = sel ? W2u : W2g;
    mc4[sel * 32 + m] = make_float4(w1[0] + w1[2] + w1[4], w1[1] + w1[3] + w1[5], b1[m], w2[m]);
    mc1[sel * 32 + m] = w2[32 + m];
  }

  // B staging: thread -> tile row brow (even=gate, odd=up of pair j0p+brow/2),
  // 8-float chunk bk8 (threads of a row read 512B contiguous). LDS: [half][row][granule^]
  const int brow = tid >> 4, bk8 = tid & 15;
  const float* srcB = ((brow & 1) ? Wu : Wg) + (size_t)(j0p + (brow >> 1)) * KGU + bk8 * 8;
  const int bwr = ((tid >> 3) & 1) * 8192 + brow * 128 + (((tid & 7) ^ (brow & 7)) << 4);

  // A fragments: wave owns 16-row tile mt=wid; 1KB contiguous per reload instr
  const short8* paB = (const short8*)XF + (size_t)wid * 64 + lane;

  f32x4 acc[4];
#pragma unroll
  for (int i = 0; i < 4; ++i) acc[i] = (f32x4)0.f;
  short8 A0, A1;
  float4 sA0, sA1, sB0, sB1;

  // prologue: B(0),B(1) regs; A kt0,kt1; B(0)->buf0; B(2)->setA
  sA0 = *(const float4*)(srcB);       sA1 = *(const float4*)(srcB + 4);
  sB0 = *(const float4*)(srcB + 128); sB1 = *(const float4*)(srcB + 132);
  A0 = paB[0]; A1 = paB[1024];
  {
    uint4 v;
    v.x = cvtpk(sA0.x, sA0.y); v.y = cvtpk(sA0.z, sA0.w);
    v.z = cvtpk(sA1.x, sA1.y); v.w = cvtpk(sA1.z, sA1.w);
    *(uint4*)(smem + bwr) = v;
  }
  sA0 = *(const float4*)(srcB + 256); sA1 = *(const float4*)(srcB + 260);
  asm volatile("s_waitcnt lgkmcnt(0)" ::: "memory");
  __builtin_amdgcn_sched_barrier(0);
  __builtin_amdgcn_s_barrier();

  auto kkstep = [&](const char* bb, int gbase, short8& Au, int ktn) {
    const int g = ((gbase + quad) ^ (s_ & 7)) << 4;
    const char* p = bb + s_ * 128 + g;
    short8 b0 = *(const short8*)(p);
    short8 b1 = *(const short8*)(p + 2048);
    short8 b2 = *(const short8*)(p + 4096);
    short8 b3 = *(const short8*)(p + 6144);
    __builtin_amdgcn_s_setprio(1);
    acc[0] = MFMA16(Au, b0, acc[0]);
    acc[1] = MFMA16(Au, b1, acc[1]);
    acc[2] = MFMA16(Au, b2, acc[2]);
    acc[3] = MFMA16(Au, b3, acc[3]);
    __builtin_amdgcn_s_setprio(0);
    Au = paB[(size_t)ktn * 1024];                      // A prefetch (dist-2 kt)
  };
  auto period = [&](int st, float4& W0, float4& W1) {
    const char* buf = smem + (st & 1) * 16384;
    const int base = st * 4;
    kkstep(buf,        0, A0, (base + 2 > 159) ? 159 : base + 2);
    kkstep(buf,        4, A1, (base + 3 > 159) ? 159 : base + 3);
    kkstep(buf + 8192, 0, A0, (base + 4 > 159) ? 159 : base + 4);
    kkstep(buf + 8192, 4, A1, (base + 5 > 159) ? 159 : base + 5);
    if (st < 39) {
      char* bufn = smem + ((st + 1) & 1) * 16384;
      uint4 v;
      v.x = cvtpk(W0.x, W0.y); v.y = cvtpk(W0.z, W0.w);
      v.z = cvtpk(W1.x, W1.y); v.w = cvtpk(W1.z, W1.w);
      *(uint4*)(bufn + bwr) = v;                       // stage B(st+1)
      const int stf = (st + 3 > 39) ? 39 : st + 3;     // reload set <- B(st+3)
      W0 = *(const float4*)(srcB + stf * 128);
      W1 = *(const float4*)(srcB + stf * 128 + 4);
      asm volatile("s_waitcnt lgkmcnt(0)" ::: "memory");
      __builtin_amdgcn_sched_barrier(0);
      __builtin_amdgcn_s_barrier();
    }
  };

#pragma unroll 1
  for (int sp = 0; sp < 20; ++sp) {                    // 40 periods
    period(2 * sp,     sB0, sB1);
    period(2 * sp + 1, sA0, sA1);
  }

  // ---- fused epilogue: qrun per lane (gate even / up odd), shfl pair, silu*up -> HF ----
  const int sel = lane & 1;
  const float b2v0 = sel ? b2u[0] : b2g[0];
  const float b2v1 = sel ? b2u[1] : b2g[1];
  const float4* mcs = mc4 + sel * 32;
  const float*  mcw = mc1 + sel * 32;
  char* HFb = (char*)HF;
#pragma unroll
  for (int ni = 0; ni < 4; ++ni) {
    const int c = ni * 16 + s_;
    const int j = j0p + (c >> 1);
    const float bp = sel ? bu[j] : bg[j];
    float sv[4], cv[4], o0[4], o1[4];
#pragma unroll
    for (int e = 0; e < 4; ++e) {
      float p = acc[ni][e] + bp;
      sv[e] = __sinf(p); cv[e] = __cosf(p);
      o0[e] = b2v0; o1[e] = b2v1;
    }
#pragma unroll 4
    for (int m = 0; m < 32; ++m) {
      float4 k4 = mcs[m]; float w2b = mcw[m];
#pragma unroll
      for (int e = 0; e < 4; ++e) {
        float hh = fmaxf(fmaf(sv[e], k4.x, fmaf(cv[e], k4.y, k4.z)), 0.f);
        o0[e] = fmaf(hh, k4.w, o0[e]);
        o1[e] = fmaf(hh, w2b, o1[e]);
      }
    }
#pragma unroll
    for (int e = 0; e < 4; ++e) {
      float t0 = __shfl_xor(o0[e], 1);
      float t1 = __shfl_xor(o1[e], 1);
      float g0 = sel ? t0 : o0[e];
      float u0 = sel ? o0[e] : t0;
      float g1 = sel ? t1 : o1[e];
      float u1 = sel ? o1[e] : t1;
      float h0 = silu(g0) * u0, h1 = silu(g1) * u1;
      if (!sel) {
        const int row = wid * 16 + quad * 4 + e;
        const int kt2 = j >> 4;
        const int lf2 = (row & 15) + 16 * ((j >> 2) & 3);
        *(uint32_t*)(HFb + ((size_t)(kt2 * 16 + wid) * 64 + lf2) * 16 + (j & 3) * 4)
            = pk2(h0, h1);
      }
    }
  }
}

// ---------------- kernel 2: down GEMM, BM=256 x BN=64, SK=128, splitK=12 ----------------
// Same structure; grid 480 (8x60 XCD-chunked) -> 30 waves/CU cap. 18 periods.
__global__ __launch_bounds__(1024, 6)
void k_down(const u16* __restrict__ HF, const float* __restrict__ Wd, float* __restrict__ P2) {
  __shared__ __align__(16) char smem[32768];
  const int tid = threadIdx.x, lane = tid & 63, wid = tid >> 6;
  const int s_ = lane & 15, quad = lane >> 4;
  const int bx = blockIdx.x;
  const int w = (bx & 7) * 60 + (bx >> 3);
  const int sk = w / 40, nt = w - sk * 40;
  const int n0 = nt * 64;

  const int brow = tid >> 4, bk8 = tid & 15;
  const float* srcB = Wd + (size_t)(n0 + brow) * KD + sk * KCHD + bk8 * 8;
  const int bwr = ((tid >> 3) & 1) * 8192 + brow * 128 + (((tid & 7) ^ (brow & 7)) << 4);

  const short8* paB = (const short8*)HF + ((size_t)(sk * 72) * 16 + wid) * 64 + lane;

  f32x4 acc[4];
#pragma unroll
  for (int i = 0; i < 4; ++i) acc[i] = (f32x4)0.f;
  short8 A0, A1;
  float4 sA0, sA1, sB0, sB1;

  sA0 = *(const float4*)(srcB);       sA1 = *(const float4*)(srcB + 4);
  sB0 = *(const float4*)(srcB + 128); sB1 = *(const float4*)(srcB + 132);
  A0 = paB[0]; A1 = paB[1024];
  {
    uint4 v;
    v.x = cvtpk(sA0.x, sA0.y); v.y = cvtpk(sA0.z, sA0.w);
    v.z = cvtpk(sA1.x, sA1.y); v.w = cvtpk(sA1.z, sA1.w);
    *(uint4*)(smem + bwr) = v;
  }
  sA0 = *(const float4*)(srcB + 256); sA1 = *(const float4*)(srcB + 260);
  asm volatile("s_waitcnt lgkmcnt(0)" ::: "memory");
  __builtin_amdgcn_sched_barrier(0);
  __builtin_amdgcn_s_barrier();

  auto kkstep = [&](const char* bb, int gbase, short8& Au, int ktn) {
    const int g = ((gbase + quad) ^ (s_ & 7)) << 4;
    const char* p = bb + s_ * 128 + g;
    short8 b0 = *(const short8*)(p);
    short8 b1 = *(const short8*)(p + 2048);
    short8 b2 = *(const short8*)(p + 4096);
    short8 b3 = *(const short8*)(p + 6144);
    __builtin_amdgcn_s_setprio(1);
    acc[0] = MFMA16(Au, b0, acc[0]);
    acc[1] = MFMA16(Au, b1, acc[1]);
    acc[2] = MFMA16(Au, b2, acc[2]);
    acc[3] = MFMA16(Au, b3, acc[3]);
    __builtin_amdgcn_s_setprio(0);
    Au = paB[(size_t)ktn * 1024];
  };
  auto period = [&](int st, float4& W0, float4& W1) {
    const char* buf = smem + (st & 1) * 16384;
    const int base = st * 4;
    kkstep(buf,        0, A0, (base + 2 > 71) ? 71 : base + 2);
    kkstep(buf,        4, A1, (base + 3 > 71) ? 71 : base + 3);
    kkstep(buf + 8192, 0, A0, (base + 4 > 71) ? 71 : base + 4);
    kkstep(buf + 8192, 4, A1, (base + 5 > 71) ? 71 : base + 5);
    if (st < 17) {
      char* bufn = smem + ((st + 1) & 1) * 16384;
      uint4 v;
      v.x = cvtpk(W0.x, W0.y); v.y = cvtpk(W0.z, W0.w);
      v.z = cvtpk(W1.x, W1.y); v.w = cvtpk(W1.z, W1.w);
      *(uint4*)(bufn + bwr) = v;
      const int stf = (st + 3 > 17) ? 17 : st + 3;
      W0 = *(const float4*)(srcB + stf * 128);
      W1 = *(const float4*)(srcB + stf * 128 + 4);
      asm volatile("s_waitcnt lgkmcnt(0)" ::: "memory");
      __builtin_amdgcn_sched_barrier(0);
      __builtin_amdgcn_s_barrier();
    }
  };

#pragma unroll 1
  for (int sp = 0; sp < 9; ++sp) {                     // 18 periods
    period(2 * sp,     sB0, sB1);
    period(2 * sp + 1, sA0, sA1);
  }

  float* P = P2 + (size_t)sk * PEL;
#pragma unroll
  for (int ni = 0; ni < 4; ++ni) {
    const int n = n0 + ni * 16 + s_;
#pragma unroll
    for (int e = 0; e < 4; ++e)
      P[(size_t)(wid * 16 + quad * 4 + e) * NPD + n] = acc[ni][e];
  }
}

// ---------------- kernel 3: reduce partials + QRUN-d epilogue -> out fp32 ----------------
__global__ __launch_bounds__(256) void k_fin(const float* __restrict__ P2, const float* __restrict__ bd,
    const float* __restrict__ W1d, const float* __restrict__ b1d, const float* __restrict__ W2d,
    const float* __restrict__ b2d, float* __restrict__ out) {
  __shared__ float4 mc0[32];
  __shared__ float mc1[32];
  const int tid = threadIdx.x;
  if (tid < 32) {
    const float* w = W1d + tid * 6;
    mc0[tid] = make_float4(w[0] + w[2] + w[4], w[1] + w[3] + w[5], b1d[tid], W2d[tid]);
    mc1[tid] = W2d[32 + tid];
  }
  __syncthreads();
  const int idx = blockIdx.x * 256 + tid;
  const int m = idx / NPD, j = idx - m * NPD;
  float p = bd[j];
#pragma unroll
  for (int sk = 0; sk < SPLITD; ++sk) p += P2[(size_t)sk * PEL + idx];
  float s = __sinf(p), c = __cosf(p);
  float o0 = b2d[0], o1 = b2d[1];
#pragma unroll 4
  for (int mm = 0; mm < 32; ++mm) {
    float4 k = mc0[mm];
    float hh = fmaxf(fmaf(s, k.x, fmaf(c, k.y, k.z)), 0.f);
    o0 = fmaf(hh, k.w, o0);
    o1 = fmaf(hh, mc1[mm], o1);
  }
  *(float2*)&out[(size_t)m * 5120 + 2 * j] = make_float2(o0, o1);
}

extern "C" void kernel_launch(void* const* d_in, const int* in_sizes, int n_in,
                              void* d_out, int out_size, void* d_ws, size_t ws_size,
                              hipStream_t stream) {
  const float* x   = (const float*)d_in[0];
  const float* Wg  = (const float*)d_in[1];
  const float* bg  = (const float*)d_in[2];
  const float* W1g = (const float*)d_in[3];
  const float* b1g = (const float*)d_in[4];
  const float* W2g = (const float*)d_in[5];
  const float* b2g = (const float*)d_in[6];
  const float* Wu  = (const float*)d_in[7];
  const float* bu  = (const float*)d_in[8];
  const float* W1u = (const float*)d_in[9];
  const float* b1u = (const float*)d_in[10];
  const float* W2u = (const float*)d_in[11];
  const float* b2u = (const float*)d_in[12];
  const float* Wd  = (const float*)d_in[13];
  const float* bd  = (const float*)d_in[14];
  const float* W1d = (const float*)d_in[15];
  const float* b1d = (const float*)d_in[16];
  const float* W2d = (const float*)d_in[17];
  const float* b2d = (const float*)d_in[18];
  char* ws = (char*)d_ws;
  u16*  XF = (u16*)ws;                     // 2,621,440 B
  u16*  HF = (u16*)(ws + 2621440);         // 14,155,776 B (ends 16,777,216)
  float* P2 = (float*)(ws + 16777216);     // 31,457,280 B
  if (ws_size < 48234496u) return;

  k_cvt<<<dim3(160), dim3(256), 0, stream>>>(x, XF);
  k_gu<<<dim3(432), dim3(1024), 0, stream>>>(XF, Wg, bg, W1g, b1g, W2g, b2g,
                                             Wu, bu, W1u, b1u, W2u, b2u, HF);
  k_down<<<dim3(480), dim3(1024), 0, stream>>>(HF, Wd, P2);
  k_fin<<<dim3(2560), dim3(256), 0, stream>>>(P2, bd, W1d, b1d, W2d, b2d, (float*)d_out);
}